// Round 9
// baseline (140.661 us; speedup 1.0000x reference)
//
#include <hip/hip_runtime.h>
#include <stdint.h>

#define N 2048
#define TILE 128
#define BK 32
#define KQ 16            // K-steps per quarter-pipeline (4 quarters x 16 x 32 = 2048)
#define LDSW 40          // u16 row stride: 80 B rows, 16B-aligned; frag reads 2 lanes/bank (free)
#define XSTR 68          // f32 row stride for exchange slots: q*4*68 mod 32 = {0,16} -> conflict-free
#define NN ((size_t)N * (size_t)N)

typedef unsigned short u16;
typedef __bf16 bf16x8 __attribute__((ext_vector_type(8)));
typedef unsigned short ushortx8 __attribute__((ext_vector_type(8)));
typedef float floatx4 __attribute__((ext_vector_type(4)));

static __device__ __forceinline__ u16 f2bf(float f) {
  unsigned int u = __builtin_bit_cast(unsigned int, f);
  return (u16)((u + 0x7fffu + ((u >> 16) & 1u)) >> 16);  // RNE, finite inputs
}
static __device__ __forceinline__ float bf2f(u16 h) {
  unsigned int u = ((unsigned int)h) << 16;
  return __builtin_bit_cast(float, u);
}

// ---------------------------------------------------------------------------
// cast + transpose: Ab[r][c] = bf16(A[r][c]); Abt[c][r] = bf16(A[r][c])
// ---------------------------------------------------------------------------
__global__ void cast_tr(const float* __restrict__ A, u16* __restrict__ Ab,
                        u16* __restrict__ Abt) {
  __shared__ float tile[32][33];
  const int tx = threadIdx.x, ty = threadIdx.y;
  const int c = blockIdx.x * 32 + tx;
#pragma unroll
  for (int i = 0; i < 4; i++) {
    const int r = blockIdx.y * 32 + ty + i * 8;
    const float v = A[(size_t)r * N + c];
    Ab[(size_t)r * N + c] = f2bf(v);
    tile[ty + i * 8][tx] = v;
  }
  __syncthreads();
  const int r2 = blockIdx.y * 32 + tx;
#pragma unroll
  for (int i = 0; i < 4; i++) {
    const int c2 = blockIdx.x * 32 + ty + i * 8;
    Abt[(size_t)c2 * N + r2] = f2bf(tile[tx][ty + i * 8]);
  }
}

// ---------------------------------------------------------------------------
// GEMM core: C = L[128 x N] * R[N x 128] (Rt stored [n][k]).
// NEW GEOMETRY (the untested matrix cell): 64x64 wave tiles AND 16 waves.
// 1024 threads = 16 waves = 4 output positions x split-K-4. Quarter k = w>>2
// processes K in [k*512,(k+1)*512) in its own double-buffered pipeline
// (16 steps of BK=32); position p = w&3 -> (wr,wc)=((p>>1)*64,(p&1)*64).
// Per CU-step: 128 frag-reads (vs R4's 192, -33% on the binding LDS pipe) +
// 64 staging writes; 4 waves/SIMD kept (R5 showed 2/SIMD loses).
// acc[4][4] = 64 VGPR; stage = 4 named ushortx8 (depth-1, rule #20-safe);
// reg-staging kept (R8: gload_lds + barrier vmcnt-drain regressed).
// One barrier per step (proven R2-R8). LDS = 163,840 B (exactly the 160 KiB
// pool; 147,456 proved launchable+exact in R4).
// Epilogue: 2-round K-quarter reduction tree through LDS (aliases dead
// staging buffers); waves with (k&1)==0 finalize a 64x32 block.
// RULE #20: all register arrays statically indexed; runtime-k selects
// VALUES via ternary / wave-uniform branches only.
// ---------------------------------------------------------------------------
__device__ __forceinline__ void gemm_core(const u16* __restrict__ L,
                                          const u16* __restrict__ Rt,
                                          int row0, int col0,
                                          float res[4][8]) {
  __shared__ __align__(16) u16 AB[2][4][2][TILE * LDSW];  // [A|B][qtr][buf] = 163,840 B
  static_assert(sizeof(u16) * 2 * 4 * 2 * TILE * LDSW == 163840, "LDS size");

  const int t = threadIdx.x;             // 0..1023
  const int lane = t & 63;
  const int w = t >> 6;                  // 0..15
  const int k = w >> 2;                  // K-quarter
  const int p = w & 3;                   // output position
  const int tl = t & 255;                // thread within quarter

  // staging map (per quarter, 256 threads): tile is 128 rows x 32 cols =
  // 512 x 16B chunks; thread tl covers chunk tl (rows 0..63) and 256+tl
  // (rows 64..127): row = ci>>2, chunk = ci&3.
  const int srow = tl >> 2;              // 0..63
  const int sch = (tl & 3) * 8;          // u16 offset
  const u16* gA0 = L + (size_t)(row0 + srow) * N + k * (KQ * BK) + sch;
  const u16* gA1 = gA0 + (size_t)64 * N;
  const u16* gB0 = Rt + (size_t)(col0 + srow) * N + k * (KQ * BK) + sch;
  const u16* gB1 = gB0 + (size_t)64 * N;
  const int w0 = srow * LDSW + sch;
  const int w1 = w0 + 64 * LDSW;

  const int lr = lane & 15;
  const int q = lane >> 4;
  const int wr = (p >> 1) * 64;
  const int wc = (p & 1) * 64;
  const int abase = (wr + lr) * LDSW + q * 8;
  const int bbase = (wc + lr) * LDSW + q * 8;

  floatx4 acc[4][4];
#pragma unroll
  for (int i = 0; i < 4; i++)
#pragma unroll
    for (int j = 0; j < 4; j++) acc[i][j] = (floatx4){0.f, 0.f, 0.f, 0.f};

  // prologue: tile 0 of this quarter -> buf 0
  {
    const ushortx8 pa0 = *(const ushortx8*)gA0;
    const ushortx8 pa1 = *(const ushortx8*)gA1;
    const ushortx8 pb0 = *(const ushortx8*)gB0;
    const ushortx8 pb1 = *(const ushortx8*)gB1;
    *(ushortx8*)&AB[0][k][0][w0] = pa0;
    *(ushortx8*)&AB[0][k][0][w1] = pa1;
    *(ushortx8*)&AB[1][k][0][w0] = pb0;
    *(ushortx8*)&AB[1][k][0][w1] = pb1;
  }
  __syncthreads();

  // step i: issue loads of tile i+1 (regs, latency hidden by compute);
  // compute on buf[cur]; write tile i+1 into buf[nxt] (its readers drained
  // before the previous barrier); one barrier.
#define GSTEP(i, cur, nxt)                                                    \
  {                                                                           \
    ushortx8 pa0, pa1, pb0, pb1;                                              \
    if ((i) + 1 < KQ) {                                                       \
      pa0 = *(const ushortx8*)(gA0 + ((i) + 1) * BK);                         \
      pa1 = *(const ushortx8*)(gA1 + ((i) + 1) * BK);                         \
      pb0 = *(const ushortx8*)(gB0 + ((i) + 1) * BK);                         \
      pb1 = *(const ushortx8*)(gB1 + ((i) + 1) * BK);                         \
    }                                                                         \
    bf16x8 af[4], bfr[4];                                                     \
    _Pragma("unroll") for (int mt = 0; mt < 4; mt++) af[mt] =                 \
        __builtin_bit_cast(bf16x8,                                            \
            *(const ushortx8*)&AB[0][k][cur][abase + mt * 16 * LDSW]);        \
    _Pragma("unroll") for (int nt = 0; nt < 4; nt++) bfr[nt] =                \
        __builtin_bit_cast(bf16x8,                                            \
            *(const ushortx8*)&AB[1][k][cur][bbase + nt * 16 * LDSW]);        \
    _Pragma("unroll") for (int mt = 0; mt < 4; mt++)                          \
        _Pragma("unroll") for (int nt = 0; nt < 4; nt++) acc[mt][nt] =        \
            __builtin_amdgcn_mfma_f32_16x16x32_bf16(af[mt], bfr[nt],          \
                                                    acc[mt][nt], 0, 0, 0);    \
    if ((i) + 1 < KQ) {                                                       \
      *(ushortx8*)&AB[0][k][nxt][w0] = pa0;                                   \
      *(ushortx8*)&AB[0][k][nxt][w1] = pa1;                                   \
      *(ushortx8*)&AB[1][k][nxt][w0] = pb0;                                   \
      *(ushortx8*)&AB[1][k][nxt][w1] = pb1;                                   \
    }                                                                         \
    __syncthreads();                                                          \
  }

  for (int io = 0; io < KQ; io += 2) {
    GSTEP(io, 0, 1)
    GSTEP(io + 1, 1, 0)
  }
#undef GSTEP

  // --- K-quarter reduction tree (aliases dead staging LDS; all reads were
  // lgkm-drained before the final loop barrier). 8 slots x 64 x XSTR f32 =
  // 139,264 B <= 163,840. Round 1: odd quarters ship full acc to slot
  // (p*2 + (k>>1)); even quarters add. Round 2: k==0 ships cols 32..63 to
  // slot p*2+1, k==2 ships cols 0..31 to slot p*2; each finalizes its half.
  float* red = (float*)&AB[0][0][0][0];
  const int slot1 = (p * 2 + (k >> 1)) * (64 * XSTR);
  if (k & 1) {
#pragma unroll
    for (int mt = 0; mt < 4; mt++)
#pragma unroll
      for (int nt = 0; nt < 4; nt++)
#pragma unroll
        for (int r = 0; r < 4; r++)
          red[slot1 + (mt * 16 + q * 4 + r) * XSTR + nt * 16 + lr] =
              acc[mt][nt][r];
  }
  __syncthreads();
  if (!(k & 1)) {
#pragma unroll
    for (int mt = 0; mt < 4; mt++)
#pragma unroll
      for (int nt = 0; nt < 4; nt++)
#pragma unroll
        for (int r = 0; r < 4; r++)
          acc[mt][nt][r] +=
              red[slot1 + (mt * 16 + q * 4 + r) * XSTR + nt * 16 + lr];
  }
  __syncthreads();
  // round 2 (slots reused after barrier)
  if (k == 0) {
    const int s = (p * 2 + 1) * (64 * XSTR);
#pragma unroll
    for (int mt = 0; mt < 4; mt++)
#pragma unroll
      for (int j = 0; j < 2; j++)
#pragma unroll
        for (int r = 0; r < 4; r++)
          red[s + (mt * 16 + q * 4 + r) * XSTR + j * 16 + lr] =
              acc[mt][2 + j][r];
  } else if (k == 2) {
    const int s = (p * 2) * (64 * XSTR);
#pragma unroll
    for (int mt = 0; mt < 4; mt++)
#pragma unroll
      for (int j = 0; j < 2; j++)
#pragma unroll
        for (int r = 0; r < 4; r++)
          red[s + (mt * 16 + q * 4 + r) * XSTR + j * 16 + lr] = acc[mt][j][r];
  }
  __syncthreads();
  if (!(k & 1)) {
    const int s = (k == 0 ? p * 2 : p * 2 + 1) * (64 * XSTR);
#pragma unroll
    for (int mt = 0; mt < 4; mt++)
#pragma unroll
      for (int j = 0; j < 2; j++)
#pragma unroll
        for (int r = 0; r < 4; r++) {
          const float vkeep = (k == 0) ? acc[mt][j][r] : acc[mt][2 + j][r];
          res[mt][j * 4 + r] =
              vkeep + red[s + (mt * 16 + q * 4 + r) * XSTR + j * 16 + lr];
        }
  }
}

// GEMM1: Mb = bf16(A @ A)
__global__ __launch_bounds__(1024, 4) void gemm_aa(const u16* __restrict__ Ab,
                                                   const u16* __restrict__ Abt,
                                                   u16* __restrict__ Mb) {
  const int row0 = blockIdx.y * TILE, col0 = blockIdx.x * TILE;
  float res[4][8];
  gemm_core(Ab, Abt, row0, col0, res);
  const int t = threadIdx.x;
  const int lane = t & 63, w = t >> 6;
  const int k = w >> 2, p = w & 3;
  if (k & 1) return;  // shipped-only waves; no barriers after this point
  const int wr = (p >> 1) * 64, wc = (p & 1) * 64;
  const int lr = lane & 15, q = lane >> 4;
  const int cbase = col0 + wc + (k == 2 ? 32 : 0);
#pragma unroll
  for (int mt = 0; mt < 4; mt++)
#pragma unroll
    for (int r = 0; r < 4; r++) {
      const int rr = row0 + wr + mt * 16 + q * 4 + r;
#pragma unroll
      for (int j = 0; j < 2; j++)
        Mb[(size_t)rr * N + cbase + j * 16 + lr] = f2bf(res[mt][j * 4 + r]);
    }
}

// rdeg[i] = 1 / (4*rowsum(M)_i + 1)   (with reference's <=1e-10 guard)
__global__ void rowsum_k(const u16* __restrict__ Mb, float* __restrict__ rdeg) {
  const int row = blockIdx.x;
  const int t = threadIdx.x;
  const ushortx8 v = *((const ushortx8*)(Mb + (size_t)row * N) + t);
  float s = 0.f;
#pragma unroll
  for (int j = 0; j < 8; j++) s += bf2f(v[j]);
#pragma unroll
  for (int off = 32; off > 0; off >>= 1) s += __shfl_down(s, off, 64);
  __shared__ float ws[4];
  if ((t & 63) == 0) ws[t >> 6] = s;
  __syncthreads();
  if (t == 0) {
    float d = 4.f * (ws[0] + ws[1] + ws[2] + ws[3]) + 1.f;
    if (d <= 1e-10f) d = 1.f;
    rdeg[row] = 1.f / d;
  }
}

// GEMM2 + fused norm epilogue: out = (8*(M@A) + 2*A) * rdeg[row]
__global__ __launch_bounds__(1024, 4) void gemm_ma(const u16* __restrict__ Mb,
                                                   const u16* __restrict__ Abt,
                                                   const float* __restrict__ A,
                                                   const float* __restrict__ rdeg,
                                                   float* __restrict__ out) {
  const int row0 = blockIdx.y * TILE, col0 = blockIdx.x * TILE;
  float res[4][8];
  gemm_core(Mb, Abt, row0, col0, res);
  const int t = threadIdx.x;
  const int lane = t & 63, w = t >> 6;
  const int k = w >> 2, p = w & 3;
  if (k & 1) return;  // no barriers after this point
  const int wr = (p >> 1) * 64, wc = (p & 1) * 64;
  const int lr = lane & 15, q = lane >> 4;
  const int cbase = col0 + wc + (k == 2 ? 32 : 0);
#pragma unroll
  for (int mt = 0; mt < 4; mt++)
#pragma unroll
    for (int r = 0; r < 4; r++) {
      const int rr = row0 + wr + mt * 16 + q * 4 + r;
      const float rd = rdeg[rr];
#pragma unroll
      for (int j = 0; j < 2; j++) {
        const int cc = cbase + j * 16 + lr;
        out[(size_t)rr * N + cc] =
            (8.f * res[mt][j * 4 + r] + 2.f * A[(size_t)rr * N + cc]) * rd;
      }
    }
}

extern "C" void kernel_launch(void* const* d_in, const int* in_sizes, int n_in,
                              void* d_out, int out_size, void* d_ws, size_t ws_size,
                              hipStream_t stream) {
  const float* A = (const float*)d_in[0];
  // GTConv weights (d_in[1..3]) are irrelevant: softmax over a singleton axis
  // is identically 1, so each conv output is exactly 2*A.
  float* out = (float*)d_out;
  char* ws = (char*)d_ws;
  u16* Ab = (u16*)ws;                          // 8 MB bf16 A row-major
  u16* Abt = (u16*)(ws + NN * 2);              // 8 MB bf16 A transposed
  u16* Mb = (u16*)(ws + NN * 4);               // 8 MB bf16 M = A@A
  float* rdeg = (float*)(ws + NN * 6);         // 8 KB reciprocal degrees

  cast_tr<<<dim3(N / 32, N / 32), dim3(32, 8), 0, stream>>>(A, Ab, Abt);
  gemm_aa<<<dim3(N / TILE, N / TILE), 1024, 0, stream>>>(Ab, Abt, Mb);
  rowsum_k<<<N, 256, 0, stream>>>(Mb, rdeg);
  gemm_ma<<<dim3(N / TILE, N / TILE), 1024, 0, stream>>>(Mb, Abt, A, rdeg, out);
}